// Round 20
// baseline (97.808 us; speedup 1.0000x reference)
//
#include <hip/hip_runtime.h>

#define B_ 4
#define NTOK 2048
#define CCH 256
#define HH 8
#define DH 32
#define MM 64
#define DV 48           // 32 v + 3 corT + 1 ones + 12 junk (never read)
#define ROWS (B_*NTOK)  // 8192

typedef __bf16 bf16_t;
typedef bf16_t bf16x8 __attribute__((ext_vector_type(8)));
typedef float f32x4 __attribute__((ext_vector_type(4)));
typedef unsigned int u32x4 __attribute__((ext_vector_type(4)));
typedef unsigned short u16;

// fold softmax scale (Dh^-0.5) and log2(e) into Q so P = exp2(S') = exp(S*scale)
#define QSCALE (0.17677669529663687f * 1.44269504088896340f)

__device__ __forceinline__ u16 f2bf(float x) {
    unsigned u = __builtin_bit_cast(unsigned, x);
    return (u16)((u + 0x7FFFu + ((u >> 16) & 1u)) >> 16);  // RNE
}
__device__ __forceinline__ unsigned cvt_pk(float lo, float hi) {
    unsigned r;
    asm("v_cvt_pk_bf16_f32 %0, %1, %2" : "=v"(r) : "v"(lo), "v"(hi));
    return r;
}
__device__ __forceinline__ f32x4 mfma16(bf16x8 a, bf16x8 b, f32x4 c) {
    return __builtin_amdgcn_mfma_f32_16x16x32_bf16(a, b, c, 0, 0, 0);
}
#if __has_builtin(__builtin_amdgcn_exp2f)
#define EXP2(x) __builtin_amdgcn_exp2f(x)
#else
#define EXP2(x) exp2f(x)
#endif

// exp2 the 8 S^T values (2 tiles x 4 regs), pack to bf16, and transpose the
// 4x4 u32 block across lane groups {q,q+16,q+32,q+48}: result is the PV
// A-fragment: lane(g,q) = P[row q][keys 8g..8g+7]. No LDS involved.
__device__ __forceinline__ bf16x8 exp_transpose(f32x4 s0, f32x4 s1) {
    unsigned W0 = cvt_pk(EXP2(s0[0]), EXP2(s0[1]));
    unsigned W1 = cvt_pk(EXP2(s0[2]), EXP2(s0[3]));
    unsigned W2 = cvt_pk(EXP2(s1[0]), EXP2(s1[1]));
    unsigned W3 = cvt_pk(EXP2(s1[2]), EXP2(s1[3]));
    asm("v_permlane32_swap_b32 %0, %1" : "+v"(W0), "+v"(W2));
    asm("v_permlane32_swap_b32 %0, %1" : "+v"(W1), "+v"(W3));
    asm("v_permlane16_swap_b32 %0, %1" : "+v"(W0), "+v"(W2));
    asm("v_permlane16_swap_b32 %0, %1" : "+v"(W1), "+v"(W3));
    u32x4 pw; pw[0] = W0; pw[1] = W1; pw[2] = W2; pw[3] = W3;
    return __builtin_bit_cast(bf16x8, pw);
}

// ---- fused prep: x1/x2 bf16 convert, weight transposes, corT+ones, G ----
__global__ __launch_bounds__(256) void prep_k(
    const float* __restrict__ x1, const float* __restrict__ x2,
    const float* __restrict__ Wq, const float* __restrict__ Wkv,
    const float* __restrict__ Wproj, const float* __restrict__ cor,
    const float* __restrict__ Wcor, const float* __restrict__ Wm,
    u16* __restrict__ x1b, u16* __restrict__ x2b,
    u16* __restrict__ Wqt, u16* __restrict__ Wkvt, u16* __restrict__ Wprojt,
    u16* __restrict__ Vt, float* __restrict__ G) {
    int bx = blockIdx.x, tid = threadIdx.x;
    if (bx < 2048) {                       // x1/x2 -> bf16, 8 elems/thread
        const float* X = (bx < 1024) ? x1 : x2;
        u16* Xb = (bx < 1024) ? x1b : x2b;
        size_t i = (size_t)(bx & 1023) * 256 + tid;
        f32x4 a0 = *(const f32x4*)(X + i * 8);
        f32x4 a1 = *(const f32x4*)(X + i * 8 + 4);
        u32x4 w;
        w[0] = cvt_pk(a0[0], a0[1]);
        w[1] = cvt_pk(a0[2], a0[3]);
        w[2] = cvt_pk(a1[0], a1[1]);
        w[3] = cvt_pk(a1[2], a1[3]);
        *(u32x4*)(Xb + i * 8) = w;
    } else if (bx < 3072) {                // weight transpose-converts
        int r = bx - 2048;
        const float* W; u16* Wt; int N, base;
        if (r < 256)      { W = Wq;    Wt = Wqt;    N = 256; base = r; }
        else if (r < 768) { W = Wkv;   Wt = Wkvt;   N = 512; base = r - 256; }
        else              { W = Wproj; Wt = Wprojt; N = 256; base = r - 768; }
        int i = base * 256 + tid;
        int k = i / N, n = i - k * N;      // read coalesced, write strided
        Wt[(size_t)n * 256 + k] = f2bf(W[i]);
    } else if (bx < 3104) {                // Vt rows 32..35: corT + ones
        int bh = bx - 3072;
        int b2 = bh >> 3;
        for (int n = tid; n < NTOK; n += 256) {
            const float* cp = cor + ((size_t)b2 * NTOK + n) * 3;
            u16* vp = Vt + ((size_t)bh * DV + 32) * NTOK + n;
            vp[0]        = f2bf(cp[0]);
            vp[NTOK]     = f2bf(cp[1]);
            vp[2 * NTOK] = f2bf(cp[2]);
            vp[3 * NTOK] = (u16)0x3F80;
        }
    } else {                               // G[h*3+j][m] = Wcor_blk @ Wm_blk
        int idx = (bx - 3104) * 256 + tid;    // < 1536
        int m = idx & 63, hj = idx >> 6;
        int hh = hj / 3, j = hj - 3 * hh;
        float acc = 0.f;
#pragma unroll
        for (int t = 0; t < 8; t++)
            acc += Wcor[j * 64 + hh * 8 + t] * Wm[(hh * 8 + t) * 64 + m];
        G[idx] = acc;
    }
}

// ---- fused Q + KV projection GEMM (y<8: Q, y 8..15: K, y 16..23: V) ----
// Max-TLP config: 32-col c-panels, acc[2] (~36 VGPR), bounds(256,8) ->
// 3072 blocks = 12 blocks/CU = 32 resident waves. LDS-staged coalesced
// writeout: FLAT 2560-u16 panel; Q/K layout row*40+col (64 rows x <=32 cols),
// V layout col*72+row (<=32 cols x 64 rows; 144B stride, 16B-aligned).
// R19 BUG FIXED: V staging overflowed the [64][40] panel's 2nd dim (rl<=63>39).
__global__ __launch_bounds__(256, 8) void qkv_k(
    const u16* __restrict__ x1b, const u16* __restrict__ x2b,
    const u16* __restrict__ Wqt, const u16* __restrict__ Wkvt,
    u16* __restrict__ Qh, u16* __restrict__ Kh, u16* __restrict__ Vt) {
    __shared__ u16 panel[2560];         // 5 KB
    int tid = threadIdx.x;
    int lane = tid & 63, wave = tid >> 6;
    int g = lane >> 4, q = lane & 15;
    int m0 = blockIdx.x * 64 + wave * 16;
    int y = blockIdx.y;
    bool isq = y < 8;
    bool isv = y >= 16;
    const u16* Ab = isq ? x1b : x2b;
    const u16* Bt = isq ? Wqt : Wkvt;
    int c0 = (isq ? y : (isv ? y - 16 + 8 : y - 8)) * 32;   // K: 0..255, V: 256..511 in Wkvt
    f32x4 acc[2] = {};
#pragma unroll
    for (int k0 = 0; k0 < CCH; k0 += 32) {
        bf16x8 af = *(const bf16x8*)(Ab + (size_t)(m0 + q) * CCH + k0 + g * 8);
#pragma unroll
        for (int t = 0; t < 2; t++) {
            bf16x8 bfr = *(const bf16x8*)(Bt + (size_t)(c0 + t * 16 + q) * CCH + k0 + g * 8);
            acc[t] = mfma16(af, bfr, acc[t]);
        }
    }
    // stage: Q/K as row*40+col; V as col*72+row (transpose happens in LDS)
#pragma unroll
    for (int t = 0; t < 2; t++) {
#pragma unroll
        for (int r = 0; r < 4; r++) {
            int rl = wave * 16 + 4 * g + r;    // local row (n), 0..63
            int cl = t * 16 + q;               // local col (c within 32-panel), 0..31
            float v = acc[t][r];
            if (isq) v *= QSCALE;
            u16 val = f2bf(v);
            if (isv) panel[cl * 72 + rl] = val;
            else     panel[rl * 40 + cl] = val;
        }
    }
    __syncthreads();
    if (!isv) {
        // thread -> (row a = tid>>2, ch = tid&3): 8 u16 contiguous cols
        int a = tid >> 2, ch = tid & 3;
        union { u16 u[8]; u32x4 v; } buf;
#pragma unroll
        for (int j = 0; j < 8; j++) buf.u[j] = panel[a * 40 + ch * 8 + j];
        int row = blockIdx.x * 64 + a;
        int b = row >> 11, n = row & 2047;
        int c = c0 + ch * 8;                  // 8-aligned: stays within a head
        u16* dst = (isq ? Qh : Kh) + ((size_t)(b * HH + (c >> 5)) * NTOK + n) * DH + (c & 31);
        *(u32x4*)dst = buf.v;
    } else {
        // thread -> (col a = tid>>3 (32 cols), ch = tid&7): 8 u16 along n
        int a = tid >> 3, ch = tid & 7;
        union { u16 u[8]; u32x4 v; } buf;
#pragma unroll
        for (int j = 0; j < 8; j++) buf.u[j] = panel[a * 72 + ch * 8 + j];
        int cc = (y - 16) * 32 + a;           // V col 0..255
        int n0 = blockIdx.x * 64 + ch * 8;
        int b = n0 >> 11, n = n0 & 2047;
        u16* dst = Vt + ((size_t)(b * HH + (cc >> 5)) * DV + (cc & 31)) * NTOK + n;
        *(u32x4*)dst = buf.v;
    }
}

// ---- fused attention: 64 q-rows x 4 k-quarter waves per block (depth-16),
// XCD-local dispatch (grid x = bh -> wgid%8 = bh%8 pins each bh to one XCD).
// 1-deep staging + sequential q-frag processing keeps register need ~110
// (R13's 2-deep variant spilled 0.5 GB). Softmax is pure-sum -> k-partials
// combine by f32 ADDITION via one LDS exchange. ----
__global__ __launch_bounds__(256, 2) void attn_k(
    const u16* __restrict__ Qh, const u16* __restrict__ Kh, const u16* __restrict__ Vt,
    u16* __restrict__ xpre, float* __restrict__ pc) {
    __shared__ __align__(16) float cb[4][3][64][12];   // 36 KB exchange
    int bh = blockIdx.x;
    int b = bh >> 3, h = bh & 7;
    int ks = threadIdx.x >> 6;          // wave id = k-quarter (keys ks*512..+512)
    int lane = threadIdx.x & 63;
    int g = lane >> 4, q = lane & 15;
    int qbase = blockIdx.y * 64;

    const u16* Qp = Qh + ((size_t)bh * NTOK + qbase + q) * DH + g * 8;
    bf16x8 qf0 = *(const bf16x8*)Qp;
    bf16x8 qf1 = *(const bf16x8*)(Qp + 16 * DH);
    bf16x8 qf2 = *(const bf16x8*)(Qp + 32 * DH);
    bf16x8 qf3 = *(const bf16x8*)(Qp + 48 * DH);

    const u16* kp = Kh + (size_t)bh * NTOK * DH + (size_t)(ks * 512 + q) * DH + g * 8;
    const u16* Vb = Vt + (size_t)bh * DV * NTOK + (size_t)q * NTOK + ks * 512 + g * 8;

    f32x4 acc00 = {}, acc01 = {}, acc02 = {}, acc10 = {}, acc11 = {}, acc12 = {};
    f32x4 acc20 = {}, acc21 = {}, acc22 = {}, acc30 = {}, acc31 = {}, acc32 = {};
    const f32x4 zacc = {0.f, 0.f, 0.f, 0.f};
    int voff = 0;

#pragma unroll 1
    for (int t = 0; t < 16; t++) {      // 16 tiles x 32 keys = this wave's 512 keys
        bf16x8 ka = *(const bf16x8*)(kp);
        bf16x8 kb = *(const bf16x8*)(kp + 16 * DH);
        kp += 32 * DH;
        bf16x8 va = *(const bf16x8*)(Vb + voff);
        bf16x8 vb = *(const bf16x8*)(Vb + 16 * NTOK + voff);
        bf16x8 vc = *(const bf16x8*)(Vb + 32 * NTOK + voff);
        voff += 32;
        {
            f32x4 s0 = mfma16(ka, qf0, zacc);
            f32x4 s1 = mfma16(kb, qf0, zacc);
            bf16x8 pf = exp_transpose(s0, s1);
            acc00 = mfma16(pf, va, acc00);
            acc01 = mfma16(pf, vb, acc01);
            acc02 = mfma16(pf, vc, acc02);
        }
        {
            f32x4 s0 = mfma16(ka, qf1, zacc);
            f32x4 s1 = mfma16(kb, qf1, zacc);
            bf16x8 pf = exp_transpose(s0, s1);
            acc10 = mfma16(pf, va, acc10);
            acc11 = mfma16(pf, vb, acc11);
            acc12 = mfma16(pf, vc, acc12);
        }
        {
            f32x4 s0 = mfma16(ka, qf2, zacc);
            f32x4 s1 = mfma16(kb, qf2, zacc);
            bf16x8 pf = exp_transpose(s0, s1);
            acc20 = mfma16(pf, va, acc20);
            acc21 = mfma16(pf, vb, acc21);
            acc22 = mfma16(pf, vc, acc22);
        }
        {
            f32x4 s0 = mfma16(ka, qf3, zacc);
            f32x4 s1 = mfma16(kb, qf3, zacc);
            bf16x8 pf = exp_transpose(s0, s1);
            acc30 = mfma16(pf, va, acc30);
            acc31 = mfma16(pf, vb, acc31);
            acc32 = mfma16(pf, vc, acc32);
        }
    }

#define ST3(dst, x, y, z) { *(f32x4*)(dst) = x; *(f32x4*)((dst) + 4) = y; *(f32x4*)((dst) + 8) = z; }
    // publish the 3 q-frags this wave does NOT own: slot j holds frag (ks+1+j)%4
    {
        float* s0 = &cb[ks][0][lane][0];
        float* s1 = &cb[ks][1][lane][0];
        float* s2 = &cb[ks][2][lane][0];
        switch (ks) {
            case 0: ST3(s0, acc10, acc11, acc12) ST3(s1, acc20, acc21, acc22) ST3(s2, acc30, acc31, acc32) break;
            case 1: ST3(s0, acc20, acc21, acc22) ST3(s1, acc30, acc31, acc32) ST3(s2, acc00, acc01, acc02) break;
            case 2: ST3(s0, acc30, acc31, acc32) ST3(s1, acc00, acc01, acc02) ST3(s2, acc10, acc11, acc12) break;
            default: ST3(s0, acc00, acc01, acc02) ST3(s1, acc10, acc11, acc12) ST3(s2, acc20, acc21, acc22) break;
        }
    }
    __syncthreads();
    // gather: own frag + 3 senders' contributions (slot j=(ks-s-1)&3 of sender s)
    f32x4 A0, A1, A2;
    switch (ks) {
        case 0:  A0 = acc00; A1 = acc01; A2 = acc02; break;
        case 1:  A0 = acc10; A1 = acc11; A2 = acc12; break;
        case 2:  A0 = acc20; A1 = acc21; A2 = acc22; break;
        default: A0 = acc30; A1 = acc31; A2 = acc32; break;
    }
#pragma unroll
    for (int d = 1; d < 4; d++) {
        int s = (ks + d) & 3;
        int j = (ks - s - 1) & 3;
        const float* r = &cb[s][j][lane][0];
        A0 += *(const f32x4*)(r);
        A1 += *(const f32x4*)(r + 4);
        A2 += *(const f32x4*)(r + 8);
    }

    // denominator = ones-row (dv 35 -> tile 2 col 3); wave ks owns rows qbase+16ks..+16
    float inv[4];
#pragma unroll
    for (int r = 0; r < 4; r++) inv[r] = 1.0f / __shfl(A2[r], (lane & 48) | 3, 64);
#pragma unroll
    for (int r = 0; r < 4; r++) {
        size_t nrow = (size_t)b * NTOK + qbase + ks * 16 + 4 * g + r;
        u16* xp = xpre + nrow * CCH + h * DH;
        xp[q] = f2bf(A0[r] * inv[r]);
        xp[16 + q] = f2bf(A1[r] * inv[r]);
        if (q < 3) pc[nrow * 24 + h * 3 + q] = A2[r] * inv[r];
    }
}

// ---- fused epilogue: blocks 0..1023 out-projection GEMM (32-col panels);
// blocks 1024..3071 motion. Same max-TLP treatment as qkv. ----
__global__ __launch_bounds__(256, 8) void out_k(
    const u16* __restrict__ xpre, const u16* __restrict__ Wprojt,
    const float* __restrict__ bias, const float* __restrict__ pc,
    const float* __restrict__ cor, const float* __restrict__ G,
    const float* __restrict__ bm, float* __restrict__ o_x,
    float* __restrict__ o_m) {
    __shared__ float Gs[24][64];
    __shared__ float u[4][24];
    int tid = threadIdx.x;
    if (blockIdx.x < 1024) {
        // out-projection: m-panel = bx>>3, c-panel = bx&7 (32 cols)
        int bx = blockIdx.x;
        int lane = tid & 63, wave = tid >> 6;
        int g = lane >> 4, q = lane & 15;
        int m0 = (bx >> 3) * 64 + wave * 16;
        int c0 = (bx & 7) * 32;
        f32x4 acc[2] = {};
#pragma unroll
        for (int k0 = 0; k0 < CCH; k0 += 32) {
            bf16x8 af = *(const bf16x8*)(xpre + (size_t)(m0 + q) * CCH + k0 + g * 8);
#pragma unroll
            for (int t = 0; t < 2; t++) {
                bf16x8 bfr = *(const bf16x8*)(Wprojt + (size_t)(c0 + t * 16 + q) * CCH + k0 + g * 8);
                acc[t] = mfma16(af, bfr, acc[t]);
            }
        }
#pragma unroll
        for (int t = 0; t < 2; t++) {
#pragma unroll
            for (int r = 0; r < 4; r++) {
                int row = m0 + 4 * g + r;
                int c = c0 + t * 16 + q;
                o_x[(size_t)row * CCH + c] = acc[t][r] + bias[c];
            }
        }
    } else {
        // motion[tok,m] = bm[m] + sum_e (pc[tok,e] - cor[tok,e%3]) * Gs[e][m]
        for (int i = tid; i < 1536; i += 256) Gs[i >> 6][i & 63] = G[i];
        size_t tok0 = (size_t)(blockIdx.x - 1024) * 4;
        if (tid < 96) {
            int tl = tid / 24, e = tid - tl * 24;
            int j = e % 3;
            size_t token = tok0 + tl;
            u[tl][e] = pc[token * 24 + e] - cor[token * 3 + j];
        }
        __syncthreads();
        int tl = tid >> 6, m = tid & 63;
        float v = bm[m];
#pragma unroll
        for (int e = 0; e < 24; e++) v += u[tl][e] * Gs[e][m];
        o_m[(tok0 + tl) * 64 + m] = v;
    }
}

extern "C" void kernel_launch(void* const* d_in, const int* in_sizes, int n_in,
                              void* d_out, int out_size, void* d_ws, size_t ws_size,
                              hipStream_t stream) {
    const float* x1    = (const float*)d_in[0];
    const float* x2    = (const float*)d_in[1];
    const float* cor   = (const float*)d_in[2];
    const float* Wq    = (const float*)d_in[3];
    const float* Wkv   = (const float*)d_in[4];
    const float* Wcor  = (const float*)d_in[5];
    const float* Wproj = (const float*)d_in[6];
    const float* bproj = (const float*)d_in[7];
    const float* Wm    = (const float*)d_in[8];
    const float* bm    = (const float*)d_in[9];
    float* out_x = (float*)d_out;                          // [ROWS][256]
    float* out_motion = out_x + (size_t)ROWS * CCH;        // [ROWS][64]

    u16* Wqt    = (u16*)d_ws;                              // 65536
    u16* Wkvt   = Wqt + 65536;                             // 131072
    u16* Wprojt = Wkvt + 131072;                           // 65536
    u16* x1b    = Wprojt + 65536;                          // 2097152
    u16* x2b    = x1b + (size_t)2097152;
    u16* Qh     = x2b + (size_t)2097152;                   // [B*H][N][32]
    u16* Kh     = Qh + (size_t)2097152;
    u16* Vt     = Kh + (size_t)2097152;                    // [B*H][48][N]
    u16* xpre   = Vt + (size_t)3145728;                    // [ROWS][256]
    float* pcb  = (float*)(xpre + (size_t)2097152);        // [ROWS][8][3]
    float* G    = pcb + (size_t)ROWS * 24;                 // [24][64]
    // total ws use ~28.6 MB

    prep_k<<<3110, 256, 0, stream>>>(x1, x2, Wq, Wkv, Wproj, cor, Wcor, Wm,
                                     x1b, x2b, Wqt, Wkvt, Wprojt, Vt, G);
    qkv_k<<<dim3(128, 24), 256, 0, stream>>>(x1b, x2b, Wqt, Wkvt, Qh, Kh, Vt);
    attn_k<<<dim3(32, 32), 256, 0, stream>>>(Qh, Kh, Vt, xpre, pcb);
    out_k<<<3072, 256, 0, stream>>>(xpre, Wprojt, bproj, pcb, cor, G, bm,
                                    out_x, out_motion);
}

// Round 21
// 95.100 us; speedup vs baseline: 1.0285x; 1.0285x over previous
//
#include <hip/hip_runtime.h>

#define B_ 4
#define NTOK 2048
#define CCH 256
#define HH 8
#define DH 32
#define MM 64
#define DV 48           // 32 v + 3 corT + 1 ones + 12 junk (never read)
#define ROWS (B_*NTOK)  // 8192

typedef __bf16 bf16_t;
typedef bf16_t bf16x8 __attribute__((ext_vector_type(8)));
typedef float f32x4 __attribute__((ext_vector_type(4)));
typedef unsigned int u32x4 __attribute__((ext_vector_type(4)));
typedef unsigned short u16;

// fold softmax scale (Dh^-0.5) and log2(e) into Q so P = exp2(S') = exp(S*scale)
#define QSCALE (0.17677669529663687f * 1.44269504088896340f)

__device__ __forceinline__ u16 f2bf(float x) {
    unsigned u = __builtin_bit_cast(unsigned, x);
    return (u16)((u + 0x7FFFu + ((u >> 16) & 1u)) >> 16);  // RNE
}
__device__ __forceinline__ unsigned cvt_pk(float lo, float hi) {
    unsigned r;
    asm("v_cvt_pk_bf16_f32 %0, %1, %2" : "=v"(r) : "v"(lo), "v"(hi));
    return r;
}
__device__ __forceinline__ f32x4 mfma16(bf16x8 a, bf16x8 b, f32x4 c) {
    return __builtin_amdgcn_mfma_f32_16x16x32_bf16(a, b, c, 0, 0, 0);
}
#if __has_builtin(__builtin_amdgcn_exp2f)
#define EXP2(x) __builtin_amdgcn_exp2f(x)
#else
#define EXP2(x) exp2f(x)
#endif

// dummy-use pin: keeps the named value live at this program point (rule #17)
#define PIN(x) asm volatile("" :: "v"(x))

// exp2 the 8 S^T values (2 tiles x 4 regs), pack to bf16, and transpose the
// 4x4 u32 block across lane groups {q,q+16,q+32,q+48}: result is the PV
// A-fragment: lane(g,q) = P[row q][keys 8g..8g+7]. No LDS involved.
__device__ __forceinline__ bf16x8 exp_transpose(f32x4 s0, f32x4 s1) {
    unsigned W0 = cvt_pk(EXP2(s0[0]), EXP2(s0[1]));
    unsigned W1 = cvt_pk(EXP2(s0[2]), EXP2(s0[3]));
    unsigned W2 = cvt_pk(EXP2(s1[0]), EXP2(s1[1]));
    unsigned W3 = cvt_pk(EXP2(s1[2]), EXP2(s1[3]));
    asm("v_permlane32_swap_b32 %0, %1" : "+v"(W0), "+v"(W2));
    asm("v_permlane32_swap_b32 %0, %1" : "+v"(W1), "+v"(W3));
    asm("v_permlane16_swap_b32 %0, %1" : "+v"(W0), "+v"(W2));
    asm("v_permlane16_swap_b32 %0, %1" : "+v"(W1), "+v"(W3));
    u32x4 pw; pw[0] = W0; pw[1] = W1; pw[2] = W2; pw[3] = W3;
    return __builtin_bit_cast(bf16x8, pw);
}

// ---- fused prep: x1/x2 bf16 convert, weight transposes, corT+ones, G ----
__global__ __launch_bounds__(256) void prep_k(
    const float* __restrict__ x1, const float* __restrict__ x2,
    const float* __restrict__ Wq, const float* __restrict__ Wkv,
    const float* __restrict__ Wproj, const float* __restrict__ cor,
    const float* __restrict__ Wcor, const float* __restrict__ Wm,
    u16* __restrict__ x1b, u16* __restrict__ x2b,
    u16* __restrict__ Wqt, u16* __restrict__ Wkvt, u16* __restrict__ Wprojt,
    u16* __restrict__ Vt, float* __restrict__ G) {
    int bx = blockIdx.x, tid = threadIdx.x;
    if (bx < 2048) {                       // x1/x2 -> bf16, 8 elems/thread
        const float* X = (bx < 1024) ? x1 : x2;
        u16* Xb = (bx < 1024) ? x1b : x2b;
        size_t i = (size_t)(bx & 1023) * 256 + tid;
        f32x4 a0 = *(const f32x4*)(X + i * 8);
        f32x4 a1 = *(const f32x4*)(X + i * 8 + 4);
        u32x4 w;
        w[0] = cvt_pk(a0[0], a0[1]);
        w[1] = cvt_pk(a0[2], a0[3]);
        w[2] = cvt_pk(a1[0], a1[1]);
        w[3] = cvt_pk(a1[2], a1[3]);
        *(u32x4*)(Xb + i * 8) = w;
    } else if (bx < 3072) {                // weight transpose-converts
        int r = bx - 2048;
        const float* W; u16* Wt; int N, base;
        if (r < 256)      { W = Wq;    Wt = Wqt;    N = 256; base = r; }
        else if (r < 768) { W = Wkv;   Wt = Wkvt;   N = 512; base = r - 256; }
        else              { W = Wproj; Wt = Wprojt; N = 256; base = r - 768; }
        int i = base * 256 + tid;
        int k = i / N, n = i - k * N;      // read coalesced, write strided
        Wt[(size_t)n * 256 + k] = f2bf(W[i]);
    } else if (bx < 3104) {                // Vt rows 32..35: corT + ones
        int bh = bx - 3072;
        int b2 = bh >> 3;
        for (int n = tid; n < NTOK; n += 256) {
            const float* cp = cor + ((size_t)b2 * NTOK + n) * 3;
            u16* vp = Vt + ((size_t)bh * DV + 32) * NTOK + n;
            vp[0]        = f2bf(cp[0]);
            vp[NTOK]     = f2bf(cp[1]);
            vp[2 * NTOK] = f2bf(cp[2]);
            vp[3 * NTOK] = (u16)0x3F80;
        }
    } else {                               // G[h*3+j][m] = Wcor_blk @ Wm_blk
        int idx = (bx - 3104) * 256 + tid;    // < 1536
        int m = idx & 63, hj = idx >> 6;
        int hh = hj / 3, j = hj - 3 * hh;
        float acc = 0.f;
#pragma unroll
        for (int t = 0; t < 8; t++)
            acc += Wcor[j * 64 + hh * 8 + t] * Wm[(hh * 8 + t) * 64 + m];
        G[idx] = acc;
    }
}

// ---- fused Q + KV projection GEMM (y<4: Q, y 4..7: K, y 8..11: V) ----
// R18 config (best measured): 64-col panels, LDS-staged coalesced writeout
// (V staged transposed), bounds(256,6).
__global__ __launch_bounds__(256, 6) void qkv_k(
    const u16* __restrict__ x1b, const u16* __restrict__ x2b,
    const u16* __restrict__ Wqt, const u16* __restrict__ Wkvt,
    u16* __restrict__ Qh, u16* __restrict__ Kh, u16* __restrict__ Vt) {
    __shared__ u16 panel[64][72];       // 9.2 KB; 72 u16 = 144 B rows (16B-aligned)
    int tid = threadIdx.x;
    int lane = tid & 63, wave = tid >> 6;
    int g = lane >> 4, q = lane & 15;
    int m0 = blockIdx.x * 64 + wave * 16;
    bool isq = blockIdx.y < 4;
    bool isv = blockIdx.y >= 8;
    const u16* Ab = isq ? x1b : x2b;
    const u16* Bt = isq ? Wqt : Wkvt;
    int c0 = (isq ? blockIdx.y : blockIdx.y - 4) * 64;
    f32x4 acc[4] = {};
#pragma unroll
    for (int k0 = 0; k0 < CCH; k0 += 32) {
        bf16x8 af = *(const bf16x8*)(Ab + (size_t)(m0 + q) * CCH + k0 + g * 8);
#pragma unroll
        for (int t = 0; t < 4; t++) {
            bf16x8 bfr = *(const bf16x8*)(Bt + (size_t)(c0 + t * 16 + q) * CCH + k0 + g * 8);
            acc[t] = mfma16(af, bfr, acc[t]);
        }
    }
    // stage: Q/K as [row][col]; V as [col][row] (transpose happens in LDS)
#pragma unroll
    for (int t = 0; t < 4; t++) {
#pragma unroll
        for (int r = 0; r < 4; r++) {
            int rl = wave * 16 + 4 * g + r;    // local row (n)
            int cl = t * 16 + q;               // local col (c)
            float v = acc[t][r];
            if (isq) v *= QSCALE;
            u16 val = f2bf(v);
            if (isv) panel[cl][rl] = val;
            else     panel[rl][cl] = val;
        }
    }
    __syncthreads();
    // coalesced writeout: thread -> (a = tid>>2, ch = tid&3): 16 u16 contiguous
    int a = tid >> 2, ch = tid & 3;
    union { u16 u[16]; u32x4 v[2]; } buf;
#pragma unroll
    for (int j = 0; j < 16; j++) buf.u[j] = panel[a][ch * 16 + j];
    u16* dst;
    if (!isv) {
        int row = blockIdx.x * 64 + a;
        int b = row >> 11, n = row & 2047;
        int c = c0 + ch * 16;
        dst = (isq ? Qh : Kh) + ((size_t)(b * HH + (c >> 5)) * NTOK + n) * DH + (c & 31);
    } else {
        int cc = (blockIdx.y - 8) * 64 + a;
        int n0 = blockIdx.x * 64 + ch * 16;
        int b = n0 >> 11, n = n0 & 2047;
        dst = Vt + ((size_t)(b * HH + (cc >> 5)) * DV + (cc & 31)) * NTOK + n;
    }
    *(u32x4*)(dst) = buf.v[0];
    *(u32x4*)(dst + 8) = buf.v[1];
}

// ---- fused attention: 64 q-rows x 4 k-quarter waves, depth-16, 2-deep
// PIN'd register prefetch (proven to hold in R10/R11: VGPR 104, -16%).
// Per tile: PIN(other set); 4 q-frag groups on current set; current set <-
// loads for tile+2 (one full compute-tile of latency cover). VGPR ~120 stays
// in the 65..128 band -> 16 waves/CU preserved (m69). Softmax pure-sum ->
// k-partials combine by f32 ADDITION via one LDS exchange. ----
__global__ __launch_bounds__(256, 2) void attn_k(
    const u16* __restrict__ Qh, const u16* __restrict__ Kh, const u16* __restrict__ Vt,
    u16* __restrict__ xpre, float* __restrict__ pc) {
    __shared__ __align__(16) float cb[4][3][64][12];   // 36 KB exchange
    int bh = blockIdx.x;
    int b = bh >> 3, h = bh & 7;
    int ks = threadIdx.x >> 6;          // wave id = k-quarter (keys ks*512..+512)
    int lane = threadIdx.x & 63;
    int g = lane >> 4, q = lane & 15;
    int qbase = blockIdx.y * 64;

    const u16* Qp = Qh + ((size_t)bh * NTOK + qbase + q) * DH + g * 8;
    bf16x8 qf0 = *(const bf16x8*)Qp;
    bf16x8 qf1 = *(const bf16x8*)(Qp + 16 * DH);
    bf16x8 qf2 = *(const bf16x8*)(Qp + 32 * DH);
    bf16x8 qf3 = *(const bf16x8*)(Qp + 48 * DH);

    const u16* kp = Kh + (size_t)bh * NTOK * DH + (size_t)(ks * 512 + q) * DH + g * 8;
    const u16* Vb = Vt + (size_t)bh * DV * NTOK + (size_t)q * NTOK + ks * 512 + g * 8;

    f32x4 acc00 = {}, acc01 = {}, acc02 = {}, acc10 = {}, acc11 = {}, acc12 = {};
    f32x4 acc20 = {}, acc21 = {}, acc22 = {}, acc30 = {}, acc31 = {}, acc32 = {};
    const f32x4 zacc = {0.f, 0.f, 0.f, 0.f};

    // prologue: tile 0 -> set A, tile 1 -> set B; loads then run 2 tiles ahead.
    // Final overruns land in adjacent ws allocations (junk, never used).
    bf16x8 kaA = *(const bf16x8*)(kp);
    bf16x8 kbA = *(const bf16x8*)(kp + 16 * DH);
    bf16x8 vaA = *(const bf16x8*)(Vb);
    bf16x8 vbA = *(const bf16x8*)(Vb + 16 * NTOK);
    bf16x8 vcA = *(const bf16x8*)(Vb + 32 * NTOK);
    bf16x8 kaB = *(const bf16x8*)(kp + 32 * DH);
    bf16x8 kbB = *(const bf16x8*)(kp + 48 * DH);
    bf16x8 vaB = *(const bf16x8*)(Vb + 32);
    bf16x8 vbB = *(const bf16x8*)(Vb + 16 * NTOK + 32);
    bf16x8 vcB = *(const bf16x8*)(Vb + 32 * NTOK + 32);
    kp += 64 * DH;
    int voff = 64;

// one tile on set X; set Y (loaded last body) pinned live; X <- tile+2 at end
#define BODY(kaX, kbX, vaX, vbX, vcX, kaY, kbY, vaY, vbY, vcY) { \
    PIN(kaY); PIN(kbY); PIN(vaY); PIN(vbY); PIN(vcY); \
    { \
        f32x4 s0 = mfma16(kaX, qf0, zacc); \
        f32x4 s1 = mfma16(kbX, qf0, zacc); \
        bf16x8 pf = exp_transpose(s0, s1); \
        acc00 = mfma16(pf, vaX, acc00); \
        acc01 = mfma16(pf, vbX, acc01); \
        acc02 = mfma16(pf, vcX, acc02); \
    } \
    { \
        f32x4 s0 = mfma16(kaX, qf1, zacc); \
        f32x4 s1 = mfma16(kbX, qf1, zacc); \
        bf16x8 pf = exp_transpose(s0, s1); \
        acc10 = mfma16(pf, vaX, acc10); \
        acc11 = mfma16(pf, vbX, acc11); \
        acc12 = mfma16(pf, vcX, acc12); \
    } \
    { \
        f32x4 s0 = mfma16(kaX, qf2, zacc); \
        f32x4 s1 = mfma16(kbX, qf2, zacc); \
        bf16x8 pf = exp_transpose(s0, s1); \
        acc20 = mfma16(pf, vaX, acc20); \
        acc21 = mfma16(pf, vbX, acc21); \
        acc22 = mfma16(pf, vcX, acc22); \
    } \
    { \
        f32x4 s0 = mfma16(kaX, qf3, zacc); \
        f32x4 s1 = mfma16(kbX, qf3, zacc); \
        bf16x8 pf = exp_transpose(s0, s1); \
        acc30 = mfma16(pf, vaX, acc30); \
        acc31 = mfma16(pf, vbX, acc31); \
        acc32 = mfma16(pf, vcX, acc32); \
    } \
    kaX = *(const bf16x8*)(kp); \
    kbX = *(const bf16x8*)(kp + 16 * DH); \
    kp += 32 * DH; \
    vaX = *(const bf16x8*)(Vb + voff); \
    vbX = *(const bf16x8*)(Vb + 16 * NTOK + voff); \
    vcX = *(const bf16x8*)(Vb + 32 * NTOK + voff); \
    voff += 32; }

#pragma unroll 1
    for (int tp = 0; tp < 8; tp++) {    // 16 tiles = this wave's 512 keys
        BODY(kaA, kbA, vaA, vbA, vcA, kaB, kbB, vaB, vbB, vcB)
        BODY(kaB, kbB, vaB, vbB, vcB, kaA, kbA, vaA, vbA, vcA)
    }

#define ST3(dst, x, y, z) { *(f32x4*)(dst) = x; *(f32x4*)((dst) + 4) = y; *(f32x4*)((dst) + 8) = z; }
    // publish the 3 q-frags this wave does NOT own: slot j holds frag (ks+1+j)%4
    {
        float* s0 = &cb[ks][0][lane][0];
        float* s1 = &cb[ks][1][lane][0];
        float* s2 = &cb[ks][2][lane][0];
        switch (ks) {
            case 0: ST3(s0, acc10, acc11, acc12) ST3(s1, acc20, acc21, acc22) ST3(s2, acc30, acc31, acc32) break;
            case 1: ST3(s0, acc20, acc21, acc22) ST3(s1, acc30, acc31, acc32) ST3(s2, acc00, acc01, acc02) break;
            case 2: ST3(s0, acc30, acc31, acc32) ST3(s1, acc00, acc01, acc02) ST3(s2, acc10, acc11, acc12) break;
            default: ST3(s0, acc00, acc01, acc02) ST3(s1, acc10, acc11, acc12) ST3(s2, acc20, acc21, acc22) break;
        }
    }
    __syncthreads();
    // gather: own frag + 3 senders' contributions (slot j=(ks-s-1)&3 of sender s)
    f32x4 A0, A1, A2;
    switch (ks) {
        case 0:  A0 = acc00; A1 = acc01; A2 = acc02; break;
        case 1:  A0 = acc10; A1 = acc11; A2 = acc12; break;
        case 2:  A0 = acc20; A1 = acc21; A2 = acc22; break;
        default: A0 = acc30; A1 = acc31; A2 = acc32; break;
    }
#pragma unroll
    for (int d = 1; d < 4; d++) {
        int s = (ks + d) & 3;
        int j = (ks - s - 1) & 3;
        const float* r = &cb[s][j][lane][0];
        A0 += *(const f32x4*)(r);
        A1 += *(const f32x4*)(r + 4);
        A2 += *(const f32x4*)(r + 8);
    }

    // denominator = ones-row (dv 35 -> tile 2 col 3); wave ks owns rows qbase+16ks..+16
    float inv[4];
#pragma unroll
    for (int r = 0; r < 4; r++) inv[r] = 1.0f / __shfl(A2[r], (lane & 48) | 3, 64);
#pragma unroll
    for (int r = 0; r < 4; r++) {
        size_t nrow = (size_t)b * NTOK + qbase + ks * 16 + 4 * g + r;
        u16* xp = xpre + nrow * CCH + h * DH;
        xp[q] = f2bf(A0[r] * inv[r]);
        xp[16 + q] = f2bf(A1[r] * inv[r]);
        if (q < 3) pc[nrow * 24 + h * 3 + q] = A2[r] * inv[r];
    }
}

// ---- fused epilogue: blocks 0..511 out-projection GEMM; 512..2559 motion ----
__global__ __launch_bounds__(256) void out_k(
    const u16* __restrict__ xpre, const u16* __restrict__ Wprojt,
    const float* __restrict__ bias, const float* __restrict__ pc,
    const float* __restrict__ cor, const float* __restrict__ G,
    const float* __restrict__ bm, float* __restrict__ o_x,
    float* __restrict__ o_m) {
    __shared__ float Gs[24][64];
    __shared__ float u[4][24];
    int tid = threadIdx.x;
    if (blockIdx.x < 512) {
        // out-projection: m-panel = bx>>2, c-panel = bx&3
        int bx = blockIdx.x;
        int lane = tid & 63, wave = tid >> 6;
        int g = lane >> 4, q = lane & 15;
        int m0 = (bx >> 2) * 64 + wave * 16;
        int c0 = (bx & 3) * 64;
        f32x4 acc[4] = {};
#pragma unroll
        for (int k0 = 0; k0 < CCH; k0 += 32) {
            bf16x8 af = *(const bf16x8*)(xpre + (size_t)(m0 + q) * CCH + k0 + g * 8);
#pragma unroll
            for (int t = 0; t < 4; t++) {
                bf16x8 bfr = *(const bf16x8*)(Wprojt + (size_t)(c0 + t * 16 + q) * CCH + k0 + g * 8);
                acc[t] = mfma16(af, bfr, acc[t]);
            }
        }
#pragma unroll
        for (int t = 0; t < 4; t++) {
#pragma unroll
            for (int r = 0; r < 4; r++) {
                int row = m0 + 4 * g + r;
                int c = c0 + t * 16 + q;
                o_x[(size_t)row * CCH + c] = acc[t][r] + bias[c];
            }
        }
    } else {
        // motion[tok,m] = bm[m] + sum_e (pc[tok,e] - cor[tok,e%3]) * Gs[e][m]
        for (int i = tid; i < 1536; i += 256) Gs[i >> 6][i & 63] = G[i];
        size_t tok0 = (size_t)(blockIdx.x - 512) * 4;
        if (tid < 96) {
            int tl = tid / 24, e = tid - tl * 24;
            int j = e % 3;
            size_t token = tok0 + tl;
            u[tl][e] = pc[token * 24 + e] - cor[token * 3 + j];
        }
        __syncthreads();
        int tl = tid >> 6, m = tid & 63;
        float v = bm[m];
#pragma unroll
        for (int e = 0; e < 24; e++) v += u[tl][e] * Gs[e][m];
        o_m[(tok0 + tl) * 64 + m] = v;
    }
}

extern "C" void kernel_launch(void* const* d_in, const int* in_sizes, int n_in,
                              void* d_out, int out_size, void* d_ws, size_t ws_size,
                              hipStream_t stream) {
    const float* x1    = (const float*)d_in[0];
    const float* x2    = (const float*)d_in[1];
    const float* cor   = (const float*)d_in[2];
    const float* Wq    = (const float*)d_in[3];
    const float* Wkv   = (const float*)d_in[4];
    const float* Wcor  = (const float*)d_in[5];
    const float* Wproj = (const float*)d_in[6];
    const float* bproj = (const float*)d_in[7];
    const float* Wm    = (const float*)d_in[8];
    const float* bm    = (const float*)d_in[9];
    float* out_x = (float*)d_out;                          // [ROWS][256]
    float* out_motion = out_x + (size_t)ROWS * CCH;        // [ROWS][64]

    u16* Wqt    = (u16*)d_ws;                              // 65536
    u16* Wkvt   = Wqt + 65536;                             // 131072
    u16* Wprojt = Wkvt + 131072;                           // 65536
    u16* x1b    = Wprojt + 65536;                          // 2097152
    u16* x2b    = x1b + (size_t)2097152;
    u16* Qh     = x2b + (size_t)2097152;                   // [B*H][N][32]
    u16* Kh     = Qh + (size_t)2097152;
    u16* Vt     = Kh + (size_t)2097152;                    // [B*H][48][N]
    u16* xpre   = Vt + (size_t)3145728;                    // [ROWS][256]
    float* pcb  = (float*)(xpre + (size_t)2097152);        // [ROWS][8][3]
    float* G    = pcb + (size_t)ROWS * 24;                 // [24][64]
    // total ws use ~28.6 MB

    prep_k<<<3110, 256, 0, stream>>>(x1, x2, Wq, Wkv, Wproj, cor, Wcor, Wm,
                                     x1b, x2b, Wqt, Wkvt, Wprojt, Vt, G);
    qkv_k<<<dim3(128, 12), 256, 0, stream>>>(x1b, x2b, Wqt, Wkvt, Qh, Kh, Vt);
    attn_k<<<dim3(32, 32), 256, 0, stream>>>(Qh, Kh, Vt, xpre, pcb);
    out_k<<<2560, 256, 0, stream>>>(xpre, Wprojt, bproj, pcb, cor, G, bm,
                                    out_x, out_motion);
}

// Round 23
// 93.521 us; speedup vs baseline: 1.0458x; 1.0169x over previous
//
#include <hip/hip_runtime.h>

#define B_ 4
#define NTOK 2048
#define CCH 256
#define HH 8
#define DH 32
#define MM 64
#define DV 48           // 32 v + 3 corT + 1 ones + 12 junk (never read)
#define ROWS (B_*NTOK)  // 8192

typedef __bf16 bf16_t;
typedef bf16_t bf16x8 __attribute__((ext_vector_type(8)));
typedef float f32x4 __attribute__((ext_vector_type(4)));
typedef unsigned int u32x4 __attribute__((ext_vector_type(4)));
typedef unsigned short u16;

// fold softmax scale (Dh^-0.5) and log2(e) into Q so P = exp2(S') = exp(S*scale)
#define QSCALE (0.17677669529663687f * 1.44269504088896340f)

__device__ __forceinline__ u16 f2bf(float x) {
    unsigned u = __builtin_bit_cast(unsigned, x);
    return (u16)((u + 0x7FFFu + ((u >> 16) & 1u)) >> 16);  // RNE
}
__device__ __forceinline__ unsigned cvt_pk(float lo, float hi) {
    unsigned r;
    asm("v_cvt_pk_bf16_f32 %0, %1, %2" : "=v"(r) : "v"(lo), "v"(hi));
    return r;
}
__device__ __forceinline__ f32x4 mfma16(bf16x8 a, bf16x8 b, f32x4 c) {
    return __builtin_amdgcn_mfma_f32_16x16x32_bf16(a, b, c, 0, 0, 0);
}
#if __has_builtin(__builtin_amdgcn_exp2f)
#define EXP2(x) __builtin_amdgcn_exp2f(x)
#else
#define EXP2(x) exp2f(x)
#endif

// exp2 the 8 S^T values (2 tiles x 4 regs), pack to bf16, and transpose the
// 4x4 u32 block across lane groups {q,q+16,q+32,q+48}: result is the PV
// A-fragment: lane(g,q) = P[row q][keys 8g..8g+7]. No LDS involved.
__device__ __forceinline__ bf16x8 exp_transpose(f32x4 s0, f32x4 s1) {
    unsigned W0 = cvt_pk(EXP2(s0[0]), EXP2(s0[1]));
    unsigned W1 = cvt_pk(EXP2(s0[2]), EXP2(s0[3]));
    unsigned W2 = cvt_pk(EXP2(s1[0]), EXP2(s1[1]));
    unsigned W3 = cvt_pk(EXP2(s1[2]), EXP2(s1[3]));
    asm("v_permlane32_swap_b32 %0, %1" : "+v"(W0), "+v"(W2));
    asm("v_permlane32_swap_b32 %0, %1" : "+v"(W1), "+v"(W3));
    asm("v_permlane16_swap_b32 %0, %1" : "+v"(W0), "+v"(W2));
    asm("v_permlane16_swap_b32 %0, %1" : "+v"(W1), "+v"(W3));
    u32x4 pw; pw[0] = W0; pw[1] = W1; pw[2] = W2; pw[3] = W3;
    return __builtin_bit_cast(bf16x8, pw);
}

// ---- fused prep: x1/x2 bf16 convert, weight transposes, corT+ones, G ----
__global__ __launch_bounds__(256) void prep_k(
    const float* __restrict__ x1, const float* __restrict__ x2,
    const float* __restrict__ Wq, const float* __restrict__ Wkv,
    const float* __restrict__ Wproj, const float* __restrict__ cor,
    const float* __restrict__ Wcor, const float* __restrict__ Wm,
    u16* __restrict__ x1b, u16* __restrict__ x2b,
    u16* __restrict__ Wqt, u16* __restrict__ Wkvt, u16* __restrict__ Wprojt,
    u16* __restrict__ Vt, float* __restrict__ G) {
    int bx = blockIdx.x, tid = threadIdx.x;
    if (bx < 2048) {                       // x1/x2 -> bf16, 8 elems/thread
        const float* X = (bx < 1024) ? x1 : x2;
        u16* Xb = (bx < 1024) ? x1b : x2b;
        size_t i = (size_t)(bx & 1023) * 256 + tid;
        f32x4 a0 = *(const f32x4*)(X + i * 8);
        f32x4 a1 = *(const f32x4*)(X + i * 8 + 4);
        u32x4 w;
        w[0] = cvt_pk(a0[0], a0[1]);
        w[1] = cvt_pk(a0[2], a0[3]);
        w[2] = cvt_pk(a1[0], a1[1]);
        w[3] = cvt_pk(a1[2], a1[3]);
        *(u32x4*)(Xb + i * 8) = w;
    } else if (bx < 3072) {                // weight transpose-converts
        int r = bx - 2048;
        const float* W; u16* Wt; int N, base;
        if (r < 256)      { W = Wq;    Wt = Wqt;    N = 256; base = r; }
        else if (r < 768) { W = Wkv;   Wt = Wkvt;   N = 512; base = r - 256; }
        else              { W = Wproj; Wt = Wprojt; N = 256; base = r - 768; }
        int i = base * 256 + tid;
        int k = i / N, n = i - k * N;      // read coalesced, write strided
        Wt[(size_t)n * 256 + k] = f2bf(W[i]);
    } else if (bx < 3104) {                // Vt rows 32..35: corT + ones
        int bh = bx - 3072;
        int b2 = bh >> 3;
        for (int n = tid; n < NTOK; n += 256) {
            const float* cp = cor + ((size_t)b2 * NTOK + n) * 3;
            u16* vp = Vt + ((size_t)bh * DV + 32) * NTOK + n;
            vp[0]        = f2bf(cp[0]);
            vp[NTOK]     = f2bf(cp[1]);
            vp[2 * NTOK] = f2bf(cp[2]);
            vp[3 * NTOK] = (u16)0x3F80;
        }
    } else {                               // G[h*3+j][m] = Wcor_blk @ Wm_blk
        int idx = (bx - 3104) * 256 + tid;    // < 1536
        int m = idx & 63, hj = idx >> 6;
        int hh = hj / 3, j = hj - 3 * hh;
        float acc = 0.f;
#pragma unroll
        for (int t = 0; t < 8; t++)
            acc += Wcor[j * 64 + hh * 8 + t] * Wm[(hh * 8 + t) * 64 + m];
        G[idx] = acc;
    }
}

// ---- fused Q + KV projection GEMM (y<4: Q, y 4..7: K, y 8..11: V) ----
// Best measured config: 64-col panels, LDS-staged coalesced writeout
// (V staged transposed), bounds(256,6).
__global__ __launch_bounds__(256, 6) void qkv_k(
    const u16* __restrict__ x1b, const u16* __restrict__ x2b,
    const u16* __restrict__ Wqt, const u16* __restrict__ Wkvt,
    u16* __restrict__ Qh, u16* __restrict__ Kh, u16* __restrict__ Vt) {
    __shared__ u16 panel[64][72];       // 9.2 KB; 72 u16 = 144 B rows (16B-aligned)
    int tid = threadIdx.x;
    int lane = tid & 63, wave = tid >> 6;
    int g = lane >> 4, q = lane & 15;
    int m0 = blockIdx.x * 64 + wave * 16;
    bool isq = blockIdx.y < 4;
    bool isv = blockIdx.y >= 8;
    const u16* Ab = isq ? x1b : x2b;
    const u16* Bt = isq ? Wqt : Wkvt;
    int c0 = (isq ? blockIdx.y : blockIdx.y - 4) * 64;
    f32x4 acc[4] = {};
#pragma unroll
    for (int k0 = 0; k0 < CCH; k0 += 32) {
        bf16x8 af = *(const bf16x8*)(Ab + (size_t)(m0 + q) * CCH + k0 + g * 8);
#pragma unroll
        for (int t = 0; t < 4; t++) {
            bf16x8 bfr = *(const bf16x8*)(Bt + (size_t)(c0 + t * 16 + q) * CCH + k0 + g * 8);
            acc[t] = mfma16(af, bfr, acc[t]);
        }
    }
    // stage: Q/K as [row][col]; V as [col][row] (transpose happens in LDS)
#pragma unroll
    for (int t = 0; t < 4; t++) {
#pragma unroll
        for (int r = 0; r < 4; r++) {
            int rl = wave * 16 + 4 * g + r;    // local row (n)
            int cl = t * 16 + q;               // local col (c)
            float v = acc[t][r];
            if (isq) v *= QSCALE;
            u16 val = f2bf(v);
            if (isv) panel[cl][rl] = val;
            else     panel[rl][cl] = val;
        }
    }
    __syncthreads();
    // coalesced writeout: thread -> (a = tid>>2, ch = tid&3): 16 u16 contiguous
    int a = tid >> 2, ch = tid & 3;
    union { u16 u[16]; u32x4 v[2]; } buf;
#pragma unroll
    for (int j = 0; j < 16; j++) buf.u[j] = panel[a][ch * 16 + j];
    u16* dst;
    if (!isv) {
        int row = blockIdx.x * 64 + a;
        int b = row >> 11, n = row & 2047;
        int c = c0 + ch * 16;
        dst = (isq ? Qh : Kh) + ((size_t)(b * HH + (c >> 5)) * NTOK + n) * DH + (c & 31);
    } else {
        int cc = (blockIdx.y - 8) * 64 + a;
        int n0 = blockIdx.x * 64 + ch * 16;
        int b = n0 >> 11, n = n0 & 2047;
        dst = Vt + ((size_t)(b * HH + (cc >> 5)) * DV + (cc & 31)) * NTOK + n;
    }
    *(u32x4*)(dst) = buf.v[0];
    *(u32x4*)(dst + 8) = buf.v[1];
}

// ---- fused attention: 64 q-rows x 4 k-quarter waves per block (depth-16),
// XCD-local dispatch (grid x = bh -> wgid%8 = bh%8 pins each bh to one XCD).
// bounds(256,2) is the verified-correct configuration ((256,1) miscompiled,
// R22). Softmax is pure-sum -> k-partials combine by f32 ADDITION via one
// LDS exchange. ----
__global__ __launch_bounds__(256, 2) void attn_k(
    const u16* __restrict__ Qh, const u16* __restrict__ Kh, const u16* __restrict__ Vt,
    u16* __restrict__ xpre, float* __restrict__ pc) {
    __shared__ __align__(16) float cb[4][3][64][12];   // 36 KB exchange
    int bh = blockIdx.x;
    int b = bh >> 3, h = bh & 7;
    int ks = threadIdx.x >> 6;          // wave id = k-quarter (keys ks*512..+512)
    int lane = threadIdx.x & 63;
    int g = lane >> 4, q = lane & 15;
    int qbase = blockIdx.y * 64;

    const u16* Qp = Qh + ((size_t)bh * NTOK + qbase + q) * DH + g * 8;
    bf16x8 qf0 = *(const bf16x8*)Qp;
    bf16x8 qf1 = *(const bf16x8*)(Qp + 16 * DH);
    bf16x8 qf2 = *(const bf16x8*)(Qp + 32 * DH);
    bf16x8 qf3 = *(const bf16x8*)(Qp + 48 * DH);

    const u16* kp = Kh + (size_t)bh * NTOK * DH + (size_t)(ks * 512 + q) * DH + g * 8;
    const u16* Vb = Vt + (size_t)bh * DV * NTOK + (size_t)q * NTOK + ks * 512 + g * 8;

    f32x4 acc00 = {}, acc01 = {}, acc02 = {}, acc10 = {}, acc11 = {}, acc12 = {};
    f32x4 acc20 = {}, acc21 = {}, acc22 = {}, acc30 = {}, acc31 = {}, acc32 = {};
    const f32x4 zacc = {0.f, 0.f, 0.f, 0.f};
    int voff = 0;

#pragma unroll 1
    for (int t = 0; t < 16; t++) {      // 16 tiles x 32 keys = this wave's 512 keys
        bf16x8 ka = *(const bf16x8*)(kp);
        bf16x8 kb = *(const bf16x8*)(kp + 16 * DH);
        kp += 32 * DH;
        bf16x8 va = *(const bf16x8*)(Vb + voff);
        bf16x8 vb = *(const bf16x8*)(Vb + 16 * NTOK + voff);
        bf16x8 vc = *(const bf16x8*)(Vb + 32 * NTOK + voff);
        voff += 32;
        {
            f32x4 s0 = mfma16(ka, qf0, zacc);
            f32x4 s1 = mfma16(kb, qf0, zacc);
            bf16x8 pf = exp_transpose(s0, s1);
            acc00 = mfma16(pf, va, acc00);
            acc01 = mfma16(pf, vb, acc01);
            acc02 = mfma16(pf, vc, acc02);
        }
        {
            f32x4 s0 = mfma16(ka, qf1, zacc);
            f32x4 s1 = mfma16(kb, qf1, zacc);
            bf16x8 pf = exp_transpose(s0, s1);
            acc10 = mfma16(pf, va, acc10);
            acc11 = mfma16(pf, vb, acc11);
            acc12 = mfma16(pf, vc, acc12);
        }
        {
            f32x4 s0 = mfma16(ka, qf2, zacc);
            f32x4 s1 = mfma16(kb, qf2, zacc);
            bf16x8 pf = exp_transpose(s0, s1);
            acc20 = mfma16(pf, va, acc20);
            acc21 = mfma16(pf, vb, acc21);
            acc22 = mfma16(pf, vc, acc22);
        }
        {
            f32x4 s0 = mfma16(ka, qf3, zacc);
            f32x4 s1 = mfma16(kb, qf3, zacc);
            bf16x8 pf = exp_transpose(s0, s1);
            acc30 = mfma16(pf, va, acc30);
            acc31 = mfma16(pf, vb, acc31);
            acc32 = mfma16(pf, vc, acc32);
        }
    }

#define ST3(dst, x, y, z) { *(f32x4*)(dst) = x; *(f32x4*)((dst) + 4) = y; *(f32x4*)((dst) + 8) = z; }
    // publish the 3 q-frags this wave does NOT own: slot j holds frag (ks+1+j)%4
    {
        float* s0 = &cb[ks][0][lane][0];
        float* s1 = &cb[ks][1][lane][0];
        float* s2 = &cb[ks][2][lane][0];
        switch (ks) {
            case 0: ST3(s0, acc10, acc11, acc12) ST3(s1, acc20, acc21, acc22) ST3(s2, acc30, acc31, acc32) break;
            case 1: ST3(s0, acc20, acc21, acc22) ST3(s1, acc30, acc31, acc32) ST3(s2, acc00, acc01, acc02) break;
            case 2: ST3(s0, acc30, acc31, acc32) ST3(s1, acc00, acc01, acc02) ST3(s2, acc10, acc11, acc12) break;
            default: ST3(s0, acc00, acc01, acc02) ST3(s1, acc10, acc11, acc12) ST3(s2, acc20, acc21, acc22) break;
        }
    }
    __syncthreads();
    // gather: own frag + 3 senders' contributions (slot j=(ks-s-1)&3 of sender s)
    f32x4 A0, A1, A2;
    switch (ks) {
        case 0:  A0 = acc00; A1 = acc01; A2 = acc02; break;
        case 1:  A0 = acc10; A1 = acc11; A2 = acc12; break;
        case 2:  A0 = acc20; A1 = acc21; A2 = acc22; break;
        default: A0 = acc30; A1 = acc31; A2 = acc32; break;
    }
#pragma unroll
    for (int d = 1; d < 4; d++) {
        int s = (ks + d) & 3;
        int j = (ks - s - 1) & 3;
        const float* r = &cb[s][j][lane][0];
        A0 += *(const f32x4*)(r);
        A1 += *(const f32x4*)(r + 4);
        A2 += *(const f32x4*)(r + 8);
    }

    // denominator = ones-row (dv 35 -> tile 2 col 3); wave ks owns rows qbase+16ks..+16
    float inv[4];
#pragma unroll
    for (int r = 0; r < 4; r++) inv[r] = 1.0f / __shfl(A2[r], (lane & 48) | 3, 64);
#pragma unroll
    for (int r = 0; r < 4; r++) {
        size_t nrow = (size_t)b * NTOK + qbase + ks * 16 + 4 * g + r;
        u16* xp = xpre + nrow * CCH + h * DH;
        xp[q] = f2bf(A0[r] * inv[r]);
        xp[16 + q] = f2bf(A1[r] * inv[r]);
        if (q < 3) pc[nrow * 24 + h * 3 + q] = A2[r] * inv[r];
    }
}

// ---- fused epilogue: blocks 0..511 out-projection GEMM; 512..2559 motion ----
__global__ __launch_bounds__(256) void out_k(
    const u16* __restrict__ xpre, const u16* __restrict__ Wprojt,
    const float* __restrict__ bias, const float* __restrict__ pc,
    const float* __restrict__ cor, const float* __restrict__ G,
    const float* __restrict__ bm, float* __restrict__ o_x,
    float* __restrict__ o_m) {
    __shared__ float Gs[24][64];
    __shared__ float u[4][24];
    int tid = threadIdx.x;
    if (blockIdx.x < 512) {
        // out-projection: m-panel = bx>>2, c-panel = bx&3
        int bx = blockIdx.x;
        int lane = tid & 63, wave = tid >> 6;
        int g = lane >> 4, q = lane & 15;
        int m0 = (bx >> 2) * 64 + wave * 16;
        int c0 = (bx & 3) * 64;
        f32x4 acc[4] = {};
#pragma unroll
        for (int k0 = 0; k0 < CCH; k0 += 32) {
            bf16x8 af = *(const bf16x8*)(xpre + (size_t)(m0 + q) * CCH + k0 + g * 8);
#pragma unroll
            for (int t = 0; t < 4; t++) {
                bf16x8 bfr = *(const bf16x8*)(Wprojt + (size_t)(c0 + t * 16 + q) * CCH + k0 + g * 8);
                acc[t] = mfma16(af, bfr, acc[t]);
            }
        }
#pragma unroll
        for (int t = 0; t < 4; t++) {
#pragma unroll
            for (int r = 0; r < 4; r++) {
                int row = m0 + 4 * g + r;
                int c = c0 + t * 16 + q;
                o_x[(size_t)row * CCH + c] = acc[t][r] + bias[c];
            }
        }
    } else {
        // motion[tok,m] = bm[m] + sum_e (pc[tok,e] - cor[tok,e%3]) * Gs[e][m]
        for (int i = tid; i < 1536; i += 256) Gs[i >> 6][i & 63] = G[i];
        size_t tok0 = (size_t)(blockIdx.x - 512) * 4;
        if (tid < 96) {
            int tl = tid / 24, e = tid - tl * 24;
            int j = e % 3;
            size_t token = tok0 + tl;
            u[tl][e] = pc[token * 24 + e] - cor[token * 3 + j];
        }
        __syncthreads();
        int tl = tid >> 6, m = tid & 63;
        float v = bm[m];
#pragma unroll
        for (int e = 0; e < 24; e++) v += u[tl][e] * Gs[e][m];
        o_m[(tok0 + tl) * 64 + m] = v;
    }
}

extern "C" void kernel_launch(void* const* d_in, const int* in_sizes, int n_in,
                              void* d_out, int out_size, void* d_ws, size_t ws_size,
                              hipStream_t stream) {
    const float* x1    = (const float*)d_in[0];
    const float* x2    = (const float*)d_in[1];
    const float* cor   = (const float*)d_in[2];
    const float* Wq    = (const float*)d_in[3];
    const float* Wkv   = (const float*)d_in[4];
    const float* Wcor  = (const float*)d_in[5];
    const float* Wproj = (const float*)d_in[6];
    const float* bproj = (const float*)d_in[7];
    const float* Wm    = (const float*)d_in[8];
    const float* bm    = (const float*)d_in[9];
    float* out_x = (float*)d_out;                          // [ROWS][256]
    float* out_motion = out_x + (size_t)ROWS * CCH;        // [ROWS][64]

    u16* Wqt    = (u16*)d_ws;                              // 65536
    u16* Wkvt   = Wqt + 65536;                             // 131072
    u16* Wprojt = Wkvt + 131072;                           // 65536
    u16* x1b    = Wprojt + 65536;                          // 2097152
    u16* x2b    = x1b + (size_t)2097152;
    u16* Qh     = x2b + (size_t)2097152;                   // [B*H][N][32]
    u16* Kh     = Qh + (size_t)2097152;
    u16* Vt     = Kh + (size_t)2097152;                    // [B*H][48][N]
    u16* xpre   = Vt + (size_t)3145728;                    // [ROWS][256]
    float* pcb  = (float*)(xpre + (size_t)2097152);        // [ROWS][8][3]
    float* G    = pcb + (size_t)ROWS * 24;                 // [24][64]
    // total ws use ~28.6 MB

    prep_k<<<3110, 256, 0, stream>>>(x1, x2, Wq, Wkv, Wproj, cor, Wcor, Wm,
                                     x1b, x2b, Wqt, Wkvt, Wprojt, Vt, G);
    qkv_k<<<dim3(128, 12), 256, 0, stream>>>(x1b, x2b, Wqt, Wkvt, Qh, Kh, Vt);
    attn_k<<<dim3(32, 32), 256, 0, stream>>>(Qh, Kh, Vt, xpre, pcb);
    out_k<<<2560, 256, 0, stream>>>(xpre, Wprojt, bproj, pcb, cor, G, bm,
                                    out_x, out_motion);
}